// Round 17
// baseline (12325.629 us; speedup 1.0000x reference)
//
#include <hip/hip_runtime.h>
#include <hip/hip_bf16.h>

#define LEN   4096
#define EMB   300
#define HALF  256
#define G4    1024   // 4*HALF
#define HID   512
#define OUT_N 20

#if defined(__has_builtin)
#  if __has_builtin(__builtin_amdgcn_sdot4)
#    define HAVE_SDOT4 1
#  endif
#  if __has_builtin(__builtin_amdgcn_rcpf)
#    define RCPF(x) __builtin_amdgcn_rcpf(x)
#  endif
#endif
#ifndef RCPF
#  define RCPF(x) (1.0f/(x))
#endif

typedef int v4i __attribute__((ext_vector_type(4)));
__device__ __forceinline__ v4i tov(int4 a){ v4i r; r[0]=a.x; r[1]=a.y; r[2]=a.z; r[3]=a.w; return r; }

__device__ __forceinline__ int dot4(int a, int b, int c){
#ifdef HAVE_SDOT4
  return __builtin_amdgcn_sdot4(a, b, c, false);
#else
  c += (int)(signed char)(a)     * (int)(signed char)(b);
  c += (int)(signed char)(a>>8)  * (int)(signed char)(b>>8);
  c += (int)(signed char)(a>>16) * (int)(signed char)(b>>16);
  c += (int)(a>>24)              * (int)(b>>24);
  return c;
#endif
}

__device__ __forceinline__ float sigm_(float x){ return RCPF(1.f + __expf(-x)); }
__device__ __forceinline__ float tanh_(float x){ return 2.f*RCPF(1.f + __expf(-2.f*x)) - 1.f; }
__device__ __forceinline__ float bf2f(unsigned short u){ return __uint_as_float(((unsigned)u)<<16); }

// lane-pair swap (xor 1) via DPP quad_perm[1,0,3,2] = 0xB1 — pure VALU
__device__ __forceinline__ int dpp1i(int x){
  return __builtin_amdgcn_mov_dpp(x, 0xB1, 0xF, 0xF, true);
}
__device__ __forceinline__ float dpp1f(float x){
  return __int_as_float(dpp1i(__float_as_int(x)));
}

__device__ __forceinline__ int qpack4(const float* p, float inv){
  int b0 = __float2int_rn(p[0]*inv); b0 = b0>127?127:(b0<-127?-127:b0);
  int b1 = __float2int_rn(p[1]*inv); b1 = b1>127?127:(b1<-127?-127:b1);
  int b2 = __float2int_rn(p[2]*inv); b2 = b2>127?127:(b2<-127?-127:b2);
  int b3 = __float2int_rn(p[3]*inv); b3 = b3>127?127:(b3<-127?-127:b3);
  return (b0&255) | ((b1&255)<<8) | ((b2&255)<<16) | ((b3&255)<<24);
}

// ---- prep: quantize Whh rows to i8 into TWO layouts --------------------------
// gates 0,1 (i,f)  -> WqV row-major: [(dir*2+g)*256 + unit] * 256 bytes (VALU)
// gates 2,3 (g~,o) -> WqM MFMA A-fragments over the 512-row matrix with
//   frag-row rg = 2*unit + (gate-2): wave w=rg>>7, tile m=(rg>>4)&7,
//   lane l = hi*16 + (rg&15); dword (m*4+t)*4+e holds k = 64t+16hi+4e..+3
//   (same k-map as the B build; validated in R15).
__global__ void prep_quant(const float* __restrict__ WhhF, const float* __restrict__ WhhB,
    const float* __restrict__ bihF, const float* __restrict__ bhhF,
    const float* __restrict__ bihB, const float* __restrict__ bhhB,
    signed char* __restrict__ WqV, signed char* __restrict__ WqM,
    float* __restrict__ wsc4, float* __restrict__ bsum)
{
  int r = blockIdx.x*256 + threadIdx.x;
  if (r >= 2*G4) return;
  int dir = r >> 10, rr = r & 1023;
  int gate = rr >> 8, unit = rr & 255;
  const float* Wr = (dir ? WhhB : WhhF) + (size_t)rr*HALF;
  float m = 0.f;
  #pragma unroll 4
  for (int k=0;k<HALF;k+=4){
    m = fmaxf(m, fmaxf(fmaxf(fabsf(Wr[k]),fabsf(Wr[k+1])), fmaxf(fabsf(Wr[k+2]),fabsf(Wr[k+3]))));
  }
  float inv = 127.f / fmaxf(m, 1e-30f);

  if (gate < 2){
    int* dst = (int*)(WqV + ((size_t)((dir*2 + gate)*256 + unit))*256);
    #pragma unroll 8
    for (int k=0;k<64;k++) dst[k] = qpack4(Wr + 4*k, inv);
  } else {
    int rg   = 2*unit + (gate - 2);
    int wv_  = rg >> 7;
    int mt   = (rg >> 4) & 7;
    int lrow = rg & 15;
    signed char* base = WqM + ((size_t)(dir*256 + wv_*64 + lrow))*512;
    #pragma unroll
    for (int t=0;t<4;t++){
      #pragma unroll
      for (int hi=0;hi<4;hi++){
        int* dst = (int*)(base + (size_t)hi*16*512 + (mt*4 + t)*16);
        #pragma unroll
        for (int e=0;e<4;e++){
          dst[e] = qpack4(Wr + 64*t + 16*hi + 4*e, inv);
        }
      }
    }
  }
  wsc4[(dir*256 + unit)*4 + gate] = (m/127.f)*(1.f/127.f);
  bsum[r] = dir ? (bihB[rr]+bhhB[rr]) : (bihF[rr]+bhhF[rr]);
}

// ---------------- Wv_ae = AE @ W_v_a^T + b_v_a  [20,512] --------------------
__global__ void wv_kernel(const float* __restrict__ AE, const float* __restrict__ Wv,
                          const float* __restrict__ bv, float* __restrict__ WvAE)
{
  __shared__ float ae[EMB];
  const int o = blockIdx.x, tid = threadIdx.x;
  for (int k=tid;k<EMB;k+=256) ae[k] = AE[(size_t)o*EMB+k];
  __syncthreads();
  for (int j=tid;j<HID;j+=256){
    const float* wr = Wv + (size_t)j*EMB;
    float d = 0.f;
    for (int k=0;k<EMB;k++) d += ae[k]*wr[k];
    WvAE[(size_t)o*HID + j] = d + bv[j];
  }
}

// ---- generic C[M,N] = A[idx(m),:K] * B[n,:K]^T + bias[n]; out f32 or bf16 ---
// gperm: permute output column g*256+j -> j*4+g (gate-interleaved pre layout)
__global__ __launch_bounds__(256) void gemm_tn(
    const float* __restrict__ A, int lda, const int* __restrict__ idx,
    const float* __restrict__ B, int ldb, const float* __restrict__ bias,
    float* __restrict__ Cf, __hip_bfloat16* __restrict__ Cb, int ldc,
    int M, int N, int K, int gperm)
{
  __shared__ __align__(16) float As[16][68];
  __shared__ __align__(16) float Bs[16][68];
  const int tid = threadIdx.x;
  const int bm = blockIdx.x<<6, bn = blockIdx.y<<6;
  const int lm = tid>>2;            // 0..63 row loaded by this thread
  const int lk = (tid&3)<<2;        // 0,4,8,12 k offset
  const int ty = tid>>4, tx = tid&15;
  int arow = bm + lm;
  if (idx) arow = idx[arow];
  const float* Ap = A + (size_t)arow*lda + lk;
  const float* Bp = B + (size_t)(bn+lm)*ldb + lk;
  float acc[4][4];
  #pragma unroll
  for (int i=0;i<4;i++)
    #pragma unroll
    for (int j=0;j<4;j++) acc[i][j]=0.f;

  for (int k0=0;k0<K;k0+=16){
    float4 av, bv;
    if (k0+16 <= K){
      av = *(const float4*)(Ap+k0);
      bv = *(const float4*)(Bp+k0);
    } else {
      float a0[4], b0[4];
      #pragma unroll
      for (int j=0;j<4;j++){
        int kk = k0+lk+j;
        a0[j] = (kk<K)? Ap[k0+j] : 0.f;
        b0[j] = (kk<K)? Bp[k0+j] : 0.f;
      }
      av = make_float4(a0[0],a0[1],a0[2],a0[3]);
      bv = make_float4(b0[0],b0[1],b0[2],b0[3]);
    }
    __syncthreads();
    As[lk+0][lm]=av.x; As[lk+1][lm]=av.y; As[lk+2][lm]=av.z; As[lk+3][lm]=av.w;
    Bs[lk+0][lm]=bv.x; Bs[lk+1][lm]=bv.y; Bs[lk+2][lm]=bv.z; Bs[lk+3][lm]=bv.w;
    __syncthreads();
    #pragma unroll
    for (int kk=0;kk<16;kk++){
      const float4 a = *(const float4*)(&As[kk][ty<<2]);
      const float4 b = *(const float4*)(&Bs[kk][tx<<2]);
      acc[0][0]+=a.x*b.x; acc[0][1]+=a.x*b.y; acc[0][2]+=a.x*b.z; acc[0][3]+=a.x*b.w;
      acc[1][0]+=a.y*b.x; acc[1][1]+=a.y*b.y; acc[1][2]+=a.y*b.z; acc[1][3]+=a.y*b.w;
      acc[2][0]+=a.z*b.x; acc[2][1]+=a.z*b.y; acc[2][2]+=a.z*b.z; acc[2][3]+=a.z*b.w;
      acc[3][0]+=a.w*b.x; acc[3][1]+=a.w*b.y; acc[3][2]+=a.w*b.z; acc[3][3]+=a.w*b.w;
    }
  }
  const int cm = bm+(ty<<2), cn = bn+(tx<<2);
  #pragma unroll
  for (int i=0;i<4;i++){
    #pragma unroll
    for (int j=0;j<4;j++){
      float v = acc[i][j] + (bias ? bias[cn+j] : 0.f);
      int col = cn+j;
      int pc = gperm ? (((col&255)<<2) | (col>>8)) : col;
      if (Cb) Cb[(size_t)(cm+i)*ldc + pc] = __float2bfloat16(v);
      else    Cf[(size_t)(cm+i)*ldc + pc] = v;
    }
  }
}

// -------------- persistent bidirectional LSTM scan (HYBRID, fixed) ----------
// 2 blocks x 768 threads (12 waves, 3/SIMD). WAVE SPECIALIZATION:
//   waves 0-7 (VALU, 512 thr): thread (u=t>>1, q2=t&1) owns gates i,f of unit
//     u over k-half [128q2,128q2+128): 2x32 = 64 weight dwords, RESIDENT
//     under the 88-VGPR cap (R11-proven budget). 64 sdot4/step + 2 DPP sums.
//   waves 8-11 (MFMA, 256 thr): R15-verified fragment machinery for gates
//     g~,o (512 rows): 32 A-fragments/lane, v_mfma_i32_16x16x64_i8, zero
//     restore traffic. 32 MFMAs/step/wave.
// R16's bug (units 128..255 uncovered) fixed by the 512-thread VALU region.
// Tail: q2=0 activates i,f (own full sums); q2=1 activates g~,o (gbufGO);
// DPP gathers to q2=0 for c/h. Integer sums exact -> absmax 0.001953125.
__global__ __attribute__((amdgpu_flat_work_group_size(768,768), amdgpu_waves_per_eu(3,3)))
void lstm_scan(
    const __hip_bfloat16* __restrict__ preF,   // [LEN][1024] gate-permuted [s][4u+g]
    const __hip_bfloat16* __restrict__ preB,
    const signed char* __restrict__ WqV,       // gates 0,1 row-major
    const signed char* __restrict__ WqM,       // gates 2,3 fragment-packed
    const float* __restrict__ wsc4,            // [2][256][4] unit-major scales
    float* __restrict__ hs, float* __restrict__ ht)
{
  const int dir = blockIdx.x;
  const int tid = threadIdx.x;   // 0..767
  const bool isV = (tid < 512);
  __shared__ __align__(16) int hq[2][64];      // double-buffered 256 x i8 h
  __shared__ __align__(16) int2 gbufGO[256];   // raw i32 (g~,o) sums per unit

  // ================= VALU role state (waves 0-7) =================
  const int u  = tid >> 1;       // unit 0..255 (valid when isV)
  const int q2 = tid & 1;        // k-half
  int4 wi0,wi1,wi2,wi3,wi4,wi5,wi6,wi7;
  int4 wf0,wf1,wf2,wf3,wf4,wf5,wf6,wf7;
  float4 scv = make_float4(0.f,0.f,0.f,0.f);
  const unsigned* pp = nullptr;
  float* hsp = nullptr;
  unsigned pv = 0;
  float c = 0.f;
  const int t0 = dir ? (LEN-1) : 0;
  const int pstep = dir ? -(G4/2) : (G4/2);    // dword stride per step
  const int hstep = dir ? -HID : HID;
  if (isV){
    const int4* wri = (const int4*)(WqV + ((size_t)((dir*2 + 0)*256 + u))*256 + q2*128);
    const int4* wrf = (const int4*)(WqV + ((size_t)((dir*2 + 1)*256 + u))*256 + q2*128);
    wi0=wri[0]; wi1=wri[1]; wi2=wri[2]; wi3=wri[3];
    wi4=wri[4]; wi5=wri[5]; wi6=wri[6]; wi7=wri[7];
    wf0=wrf[0]; wf1=wrf[1]; wf2=wrf[2]; wf3=wrf[3];
    wf4=wrf[4]; wf5=wrf[5]; wf6=wrf[6]; wf7=wrf[7];
#define PIN(v) asm volatile("" : "+v"(v.x),"+v"(v.y),"+v"(v.z),"+v"(v.w))
    PIN(wi0);PIN(wi1);PIN(wi2);PIN(wi3);PIN(wi4);PIN(wi5);PIN(wi6);PIN(wi7);
    PIN(wf0);PIN(wf1);PIN(wf2);PIN(wf3);PIN(wf4);PIN(wf5);PIN(wf6);PIN(wf7);
#undef PIN
    scv = ((const float4*)wsc4)[dir*256 + u];
    // pre dword: ushorts (4u + 2*q2, +1): q2=0 -> (i,f) pre, q2=1 -> (g~,o) pre
    pp = (const unsigned*)(dir ? preB : preF) + (size_t)t0*(G4/2) + (u*2 + q2);
    pv = *pp;
    hsp = hs + (size_t)t0*HID + dir*HALF + u;
  }

  // ================= MFMA role state (waves 8-11) =================
  const int l  = tid & 63;
  const int wm = (tid >> 6) - 8;               // 0..3 (valid when !isV)
  int4 m00,m01,m02,m03,m10,m11,m12,m13,m20,m21,m22,m23,m30,m31,m32,m33;
  int4 m40,m41,m42,m43,m50,m51,m52,m53,m60,m61,m62,m63,m70,m71,m72,m73;
  if (!isV){
    const int4* wp = (const int4*)(WqM + ((size_t)(dir*256 + wm*64 + l))*512);
    m00=wp[0];  m01=wp[1];  m02=wp[2];  m03=wp[3];
    m10=wp[4];  m11=wp[5];  m12=wp[6];  m13=wp[7];
    m20=wp[8];  m21=wp[9];  m22=wp[10]; m23=wp[11];
    m30=wp[12]; m31=wp[13]; m32=wp[14]; m33=wp[15];
    m40=wp[16]; m41=wp[17]; m42=wp[18]; m43=wp[19];
    m50=wp[20]; m51=wp[21]; m52=wp[22]; m53=wp[23];
    m60=wp[24]; m61=wp[25]; m62=wp[26]; m63=wp[27];
    m70=wp[28]; m71=wp[29]; m72=wp[30]; m73=wp[31];
  }

  if (tid < 64) hq[0][tid] = 0;
  __syncthreads();

  const int bbase = (l >> 4) * 16;   // B-fragment byte offset

  for (int s=0;s<LEN;s++){
    int i_full = 0, f_full = 0;
    unsigned pnext = pv;
    if (isV){
      if (s < LEN-1){ pp += pstep; pnext = *pp; }
      // ---- 64 sdot4 over own k-half: gates i and f ----
      const int4* hb = (const int4*)(&hq[s&1][0]) + q2*8;
      int ai0=0,ai1=0,af0=0,af1=0;
#define VC(cc, AI, AF, WI, WF) { int4 hv = hb[cc]; \
      AI=dot4(WI.x,hv.x,AI); AI=dot4(WI.y,hv.y,AI); AI=dot4(WI.z,hv.z,AI); AI=dot4(WI.w,hv.w,AI); \
      AF=dot4(WF.x,hv.x,AF); AF=dot4(WF.y,hv.y,AF); AF=dot4(WF.z,hv.z,AF); AF=dot4(WF.w,hv.w,AF); }
      VC(0,ai0,af0,wi0,wf0) VC(1,ai1,af1,wi1,wf1)
      VC(2,ai0,af0,wi2,wf2) VC(3,ai1,af1,wi3,wf3)
      VC(4,ai0,af0,wi4,wf4) VC(5,ai1,af1,wi5,wf5)
      VC(6,ai0,af0,wi6,wf6) VC(7,ai1,af1,wi7,wf7)
#undef VC
      i_full = ai0 + ai1; i_full += dpp1i(i_full);   // both lanes: full i-sum
      f_full = af0 + af1; f_full += dpp1i(f_full);   // both lanes: full f-sum
    } else {
      // ---- B fragments: h broadcast to all 16 cols ----
      const char* hb = (const char*)&hq[s&1][0];
      v4i B0 = tov(*(const int4*)(hb + bbase));
      v4i B1 = tov(*(const int4*)(hb +  64 + bbase));
      v4i B2 = tov(*(const int4*)(hb + 128 + bbase));
      v4i B3 = tov(*(const int4*)(hb + 192 + bbase));
      v4i a0={0,0,0,0},a1={0,0,0,0},a2={0,0,0,0},a3={0,0,0,0};
      v4i a4={0,0,0,0},a5={0,0,0,0},a6={0,0,0,0},a7={0,0,0,0};
#define MF(acc, W, B) acc = __builtin_amdgcn_mfma_i32_16x16x64_i8(tov(W), B, acc, 0, 0, 0);
      MF(a0,m00,B0) MF(a1,m10,B0) MF(a2,m20,B0) MF(a3,m30,B0)
      MF(a4,m40,B0) MF(a5,m50,B0) MF(a6,m60,B0) MF(a7,m70,B0)
      MF(a0,m01,B1) MF(a1,m11,B1) MF(a2,m21,B1) MF(a3,m31,B1)
      MF(a4,m41,B1) MF(a5,m51,B1) MF(a6,m61,B1) MF(a7,m71,B1)
      MF(a0,m02,B2) MF(a1,m12,B2) MF(a2,m22,B2) MF(a3,m32,B2)
      MF(a4,m42,B2) MF(a5,m52,B2) MF(a6,m62,B2) MF(a7,m72,B2)
      MF(a0,m03,B3) MF(a1,m13,B3) MF(a2,m23,B3) MF(a3,m33,B3)
      MF(a4,m43,B3) MF(a5,m53,B3) MF(a6,m63,B3) MF(a7,m73,B3)
#undef MF
      // ---- col-0 lanes publish (g~,o): frag row 128wm+16m+4q+r, unit=rg>>1
      if ((l & 15) == 0){
        const int q = l >> 4;
#define PUB(m_, A) { int uu = 64*wm + 8*m_ + 2*q; \
        gbufGO[uu]   = make_int2(A[0], A[1]); \
        gbufGO[uu+1] = make_int2(A[2], A[3]); }
        PUB(0,a0) PUB(1,a1) PUB(2,a2) PUB(3,a3)
        PUB(4,a4) PUB(5,a5) PUB(6,a6) PUB(7,a7)
#undef PUB
      }
    }
    __syncthreads();
    // ---- tail (VALU lanes): activate + c/h update ----
    if (isV){
      int2 go = gbufGO[u];                     // broadcast
      int   sA  = q2 ? go.x : i_full;          // q2=0: i ; q2=1: g~
      int   sB  = q2 ? go.y : f_full;          // q2=0: f ; q2=1: o
      float scA = q2 ? scv.z : scv.x;
      float scB = q2 ? scv.w : scv.y;
      float eK  = q2 ? -2.f : -1.f;            // slotA: tanh for q2=1
      float aM  = q2 ?  2.f :  1.f;
      float aB  = q2 ? -1.f :  0.f;
      float gA = bf2f((unsigned short)(pv & 0xffffu)) + (float)sA*scA;
      float gB = bf2f((unsigned short)(pv >> 16))     + (float)sB*scB;
      float yA = RCPF(1.f + __expf(eK * gA));
      float actA = fmaf(aM, yA, aB);           // q2=0: i ; q2=1: g~
      float actB = sigm_(gB);                  // q2=0: f ; q2=1: o
      float gg = dpp1f(actA);                  // q2=0 <- g~
      float oo = dpp1f(actB);                  // q2=0 <- o
      if (q2 == 0){
        c = fmaf(actB, c, actA * gg);
        float h = oo * tanh_(c);
        *hsp = h;
        ((signed char*)&hq[(s+1)&1][0])[u] = (signed char)__float2int_rn(h * 127.f);
        if (s == LEN-1) ht[dir*HALF + u] = h;
      }
      hsp += hstep;
      pv = pnext;
    }
    __syncthreads();
  }
}

// ---------------- xw = ht @ W_x_a^T + b_x_a [512] ---------------------------
__global__ __launch_bounds__(512) void xw_kernel(const float* __restrict__ ht,
    const float* __restrict__ Wx, const float* __restrict__ bx, float* __restrict__ xw)
{
  __shared__ float h[HID];
  const int tid = threadIdx.x;
  h[tid] = ht[tid];
  __syncthreads();
  const float* wr = Wx + (size_t)tid*HID;
  float d = 0.f;
  for (int k=0;k<HID;k++) d += h[k]*wr[k];
  xw[tid] = d + bx[tid];
}

// ------- scores[o,l] = w_a . tanh(Wh_out[l] + Wv_ae[o]) + b_w_a -------------
__global__ __launch_bounds__(256) void scores_kernel(
    const float* __restrict__ WhOut, const float* __restrict__ WvAE,
    const float* __restrict__ wa, const float* __restrict__ bwa,
    float* __restrict__ scores)
{
  __shared__ float red[4];
  const int l = blockIdx.x, tid = threadIdx.x;
  const int lane = tid & 63, wv = tid >> 6;
  const float wl0 = WhOut[(size_t)l*HID + tid];
  const float wl1 = WhOut[(size_t)l*HID + 256 + tid];
  const float wa0 = wa[tid], wa1 = wa[256+tid];
  const float bb = bwa[0];
  for (int o=0;o<OUT_N;o++){
    float v = wa0*tanh_(wl0 + WvAE[o*HID+tid]) + wa1*tanh_(wl1 + WvAE[o*HID+256+tid]);
    #pragma unroll
    for (int m=32;m;m>>=1) v += __shfl_xor(v, m, 64);
    if (lane==0) red[wv] = v;
    __syncthreads();
    if (tid==0) scores[(size_t)o*LEN + l] = red[0]+red[1]+red[2]+red[3] + bb;
    __syncthreads();
  }
}

// ------- softmax over l (per o) + r[o] = weights @ output2 ------------------
__global__ __launch_bounds__(512) void softmax_wsum(
    const float* __restrict__ scores, const float* __restrict__ hs, float* __restrict__ ratt)
{
  __shared__ float sm[LEN];
  __shared__ float red[8];
  __shared__ float bc[2];
  const int o = blockIdx.x, tid = threadIdx.x;
  const int lane = tid & 63, wv = tid >> 6;
  for (int l=tid;l<LEN;l+=512) sm[l] = scores[(size_t)o*LEN + l];
  __syncthreads();
  float mx = -1e30f;
  for (int l=tid;l<LEN;l+=512) mx = fmaxf(mx, sm[l]);
  #pragma unroll
  for (int m=32;m;m>>=1) mx = fmaxf(mx, __shfl_xor(mx, m, 64));
  if (lane==0) red[wv] = mx;
  __syncthreads();
  if (tid==0){ float m0=red[0]; for (int i=1;i<8;i++) m0=fmaxf(m0,red[i]); bc[0]=m0; }
  __syncthreads();
  const float m0 = bc[0];
  float s = 0.f;
  for (int l=tid;l<LEN;l+=512){ float e = __expf(sm[l]-m0); sm[l]=e; s+=e; }
  #pragma unroll
  for (int m=32;m;m>>=1) s += __shfl_xor(s, m, 64);
  if (lane==0) red[wv] = s;
  __syncthreads();
  if (tid==0){ float z=0.f; for (int i=0;i<8;i++) z+=red[i]; bc[1] = 1.f/z; }
  __syncthreads();
  const float rz = bc[1];
  float acc = 0.f;
  const float* hp = hs + tid;
  for (int l=0;l<LEN;l++) acc += sm[l]*hp[(size_t)l*HID];
  ratt[(size_t)o*HID + tid] = acc*rz;
}

// ------- out[o] = sigmoid( dec_W[o] . tanh(r W_p^T + b_p + xw) + dec_b ) ----
__global__ __launch_bounds__(256) void final_kernel(
    const float* __restrict__ ratt, const float* __restrict__ Wp, const float* __restrict__ bp,
    const float* __restrict__ xw, const float* __restrict__ decW, const float* __restrict__ decb,
    float* __restrict__ outp)
{
  __shared__ float rv[HID];
  __shared__ float rr[HID];
  __shared__ float red[4];
  const int o = blockIdx.x, tid = threadIdx.x;
  const int lane = tid & 63, wv = tid >> 6;
  rv[tid]     = ratt[(size_t)o*HID + tid];
  rv[256+tid] = ratt[(size_t)o*HID + 256 + tid];
  __syncthreads();
  #pragma unroll
  for (int jj=0;jj<2;jj++){
    int j = tid + jj*256;
    const float* wr = Wp + (size_t)j*HID;
    float d = 0.f;
    for (int k=0;k<HID;k++) d += rv[k]*wr[k];
    rr[j] = tanh_(d + bp[j] + xw[j]);
  }
  __syncthreads();
  float v = rr[tid]*decW[(size_t)o*HID+tid] + rr[256+tid]*decW[(size_t)o*HID+256+tid];
  #pragma unroll
  for (int m=32;m;m>>=1) v += __shfl_xor(v, m, 64);
  if (lane==0) red[wv] = v;
  __syncthreads();
  if (tid==0) outp[o] = sigm_(red[0]+red[1]+red[2]+red[3] + decb[o]);
}

// ---------------------------------------------------------------------------
extern "C" void kernel_launch(void* const* d_in, const int* in_sizes, int n_in,
                              void* d_out, int out_size, void* d_ws, size_t ws_size,
                              hipStream_t stream)
{
  (void)in_sizes; (void)n_in; (void)out_size; (void)ws_size;
  const int*   sent  = (const int*)  d_in[0];
  const float* embed = (const float*)d_in[1];
  const float* WihF  = (const float*)d_in[2];
  const float* WhhF  = (const float*)d_in[3];
  const float* bihF  = (const float*)d_in[4];
  const float* bhhF  = (const float*)d_in[5];
  const float* WihB  = (const float*)d_in[6];
  const float* WhhB  = (const float*)d_in[7];
  const float* bihB  = (const float*)d_in[8];
  const float* bhhB  = (const float*)d_in[9];
  const float* AE    = (const float*)d_in[10];
  const float* W_h   = (const float*)d_in[11];
  const float* b_h   = (const float*)d_in[12];
  const float* W_v   = (const float*)d_in[13];
  const float* b_v   = (const float*)d_in[14];
  const float* w_a   = (const float*)d_in[15];
  const float* b_w   = (const float*)d_in[16];
  const float* W_p   = (const float*)d_in[17];
  const float* b_p   = (const float*)d_in[18];
  const float* W_x   = (const float*)d_in[19];
  const float* b_x   = (const float*)d_in[20];
  const float* decW  = (const float*)d_in[21];
  const float* decb  = (const float*)d_in[22];
  float* outp = (float*)d_out;

  char* ws = (char*)d_ws;
  size_t off = 0;
  auto alloc = [&](size_t n){ size_t p = off; off += (n + 255) & ~(size_t)255; return p; };
  __hip_bfloat16* preF  = (__hip_bfloat16*)(ws + alloc((size_t)LEN*G4*2));
  __hip_bfloat16* preB  = (__hip_bfloat16*)(ws + alloc((size_t)LEN*G4*2));
  float*          hsbuf = (float*)        (ws + alloc((size_t)LEN*HID*4));
  float*          WhOut = (float*)        (ws + alloc((size_t)LEN*HID*4));
  signed char*    WqV   = (signed char*)  (ws + alloc((size_t)2*2*256*256));
  signed char*    WqM   = (signed char*)  (ws + alloc((size_t)2*256*512));
  float*          wsc4  = (float*)        (ws + alloc((size_t)2*HALF*4*4));
  float*          bsum  = (float*)        (ws + alloc((size_t)2*G4*4));
  float*          htv   = (float*)        (ws + alloc((size_t)HID*4));
  float*          WvAE  = (float*)        (ws + alloc((size_t)OUT_N*HID*4));
  float*          xw    = (float*)        (ws + alloc((size_t)HID*4));
  float*          scor  = (float*)        (ws + alloc((size_t)OUT_N*LEN*4));
  float*          ratt  = (float*)        (ws + alloc((size_t)OUT_N*HID*4));

  // prep
  prep_quant<<<8, 256, 0, stream>>>(WhhF, WhhB, bihF, bhhF, bihB, bhhB, WqV, WqM, wsc4, bsum);
  wv_kernel<<<OUT_N, 256, 0, stream>>>(AE, W_v, b_v, WvAE);

  // pre = gather(embed, sent) @ Wih^T + (bih+bhh), bf16, gate-permuted cols
  gemm_tn<<<dim3(LEN/64, G4/64), 256, 0, stream>>>(
      embed, EMB, sent, WihF, EMB, bsum,        nullptr, preF, G4, LEN, G4, EMB, 1);
  gemm_tn<<<dim3(LEN/64, G4/64), 256, 0, stream>>>(
      embed, EMB, sent, WihB, EMB, bsum + G4,   nullptr, preB, G4, LEN, G4, EMB, 1);

  // sequential bidirectional scan (2 persistent blocks, hybrid VALU+MFMA)
  lstm_scan<<<2, 768, 0, stream>>>(preF, preB, WqV, WqM, wsc4, hsbuf, htv);

  // Wh_out = output2 @ W_h_a^T + b_h_a
  gemm_tn<<<dim3(LEN/64, HID/64), 256, 0, stream>>>(
      hsbuf, HID, nullptr, W_h, HID, b_h, WhOut, nullptr, HID, LEN, HID, HID, 0);

  xw_kernel<<<1, 512, 0, stream>>>(htv, W_x, b_x, xw);
  scores_kernel<<<LEN, 256, 0, stream>>>(WhOut, WvAE, w_a, b_w, scor);
  softmax_wsum<<<OUT_N, 512, 0, stream>>>(scor, hsbuf, ratt);
  final_kernel<<<OUT_N, 256, 0, stream>>>(ratt, W_p, b_p, xw, decW, decb, outp);
}

// Round 18
// 3500.412 us; speedup vs baseline: 3.5212x; 3.5212x over previous
//
#include <hip/hip_runtime.h>
#include <hip/hip_bf16.h>

#define LEN   4096
#define EMB   300
#define HALF  256
#define G4    1024   // 4*HALF
#define HID   512
#define OUT_N 20

#if defined(__has_builtin)
#  if __has_builtin(__builtin_amdgcn_sdot4)
#    define HAVE_SDOT4 1
#  endif
#  if __has_builtin(__builtin_amdgcn_rcpf)
#    define RCPF(x) __builtin_amdgcn_rcpf(x)
#  endif
#endif
#ifndef RCPF
#  define RCPF(x) (1.0f/(x))
#endif

__device__ __forceinline__ int dot4(int a, int b, int c){
#ifdef HAVE_SDOT4
  return __builtin_amdgcn_sdot4(a, b, c, false);
#else
  c += (int)(signed char)(a)     * (int)(signed char)(b);
  c += (int)(signed char)(a>>8)  * (int)(signed char)(b>>8);
  c += (int)(signed char)(a>>16) * (int)(signed char)(b>>16);
  c += (int)(a>>24)              * (int)(b>>24);
  return c;
#endif
}

__device__ __forceinline__ float sigm_(float x){ return RCPF(1.f + __expf(-x)); }
__device__ __forceinline__ float tanh_(float x){ return 2.f*RCPF(1.f + __expf(-2.f*x)) - 1.f; }
__device__ __forceinline__ float bf2f(unsigned short u){ return __uint_as_float(((unsigned)u)<<16); }

// lane-pair swap (xor 1) via DPP quad_perm[1,0,3,2] = 0xB1 — pure VALU
__device__ __forceinline__ int dpp1i(int x){
  return __builtin_amdgcn_mov_dpp(x, 0xB1, 0xF, 0xF, true);
}
__device__ __forceinline__ float dpp1f(float x){
  return __int_as_float(dpp1i(__float_as_int(x)));
}

// ---------------- prep: quantize Whh rows to i8 + bias sums -----------------
__global__ void prep_quant(const float* __restrict__ WhhF, const float* __restrict__ WhhB,
    const float* __restrict__ bihF, const float* __restrict__ bhhF,
    const float* __restrict__ bihB, const float* __restrict__ bhhB,
    signed char* __restrict__ Wq, float* __restrict__ wsc, float* __restrict__ bsum)
{
  int r = blockIdx.x*256 + threadIdx.x;
  if (r >= 2*G4) return;
  int dir = r >> 10, row = r & 1023;
  const float4* Wr = (const float4*)((dir ? WhhB : WhhF) + (size_t)row*HALF);
  float m = 0.f;
  #pragma unroll 4
  for (int k=0;k<HALF/4;k++){
    float4 v = Wr[k];
    m = fmaxf(m, fmaxf(fmaxf(fabsf(v.x),fabsf(v.y)), fmaxf(fabsf(v.z),fabsf(v.w))));
  }
  float inv = 127.f / fmaxf(m, 1e-30f);
  int* q = (int*)(Wq + (size_t)r*HALF);
  #pragma unroll 4
  for (int k=0;k<HALF/4;k++){
    float4 v = Wr[k];
    int b0 = __float2int_rn(v.x*inv); b0 = b0>127?127:(b0<-127?-127:b0);
    int b1 = __float2int_rn(v.y*inv); b1 = b1>127?127:(b1<-127?-127:b1);
    int b2 = __float2int_rn(v.z*inv); b2 = b2>127?127:(b2<-127?-127:b2);
    int b3 = __float2int_rn(v.w*inv); b3 = b3>127?127:(b3<-127?-127:b3);
    q[k] = (b0&255) | ((b1&255)<<8) | ((b2&255)<<16) | ((b3&255)<<24);
  }
  wsc[r]  = (m/127.f)*(1.f/127.f);        // scale for (i32 dot) -> f32
  bsum[r] = dir ? (bihB[row]+bhhB[row]) : (bihF[row]+bhhF[row]);
}

// ---------------- Wv_ae = AE @ W_v_a^T + b_v_a  [20,512] --------------------
__global__ void wv_kernel(const float* __restrict__ AE, const float* __restrict__ Wv,
                          const float* __restrict__ bv, float* __restrict__ WvAE)
{
  __shared__ float ae[EMB];
  const int o = blockIdx.x, tid = threadIdx.x;
  for (int k=tid;k<EMB;k+=256) ae[k] = AE[(size_t)o*EMB+k];
  __syncthreads();
  for (int j=tid;j<HID;j+=256){
    const float* wr = Wv + (size_t)j*EMB;
    float d = 0.f;
    for (int k=0;k<EMB;k++) d += ae[k]*wr[k];
    WvAE[(size_t)o*HID + j] = d + bv[j];
  }
}

// ---- generic C[M,N] = A[idx(m),:K] * B[n,:K]^T + bias[n]; out f32 or bf16 ---
// gperm: permute output column g*256+j -> j*4+g (gate-interleaved pre layout)
__global__ __launch_bounds__(256) void gemm_tn(
    const float* __restrict__ A, int lda, const int* __restrict__ idx,
    const float* __restrict__ B, int ldb, const float* __restrict__ bias,
    float* __restrict__ Cf, __hip_bfloat16* __restrict__ Cb, int ldc,
    int M, int N, int K, int gperm)
{
  __shared__ __align__(16) float As[16][68];
  __shared__ __align__(16) float Bs[16][68];
  const int tid = threadIdx.x;
  const int bm = blockIdx.x<<6, bn = blockIdx.y<<6;
  const int lm = tid>>2;            // 0..63 row loaded by this thread
  const int lk = (tid&3)<<2;        // 0,4,8,12 k offset
  const int ty = tid>>4, tx = tid&15;
  int arow = bm + lm;
  if (idx) arow = idx[arow];
  const float* Ap = A + (size_t)arow*lda + lk;
  const float* Bp = B + (size_t)(bn+lm)*ldb + lk;
  float acc[4][4];
  #pragma unroll
  for (int i=0;i<4;i++)
    #pragma unroll
    for (int j=0;j<4;j++) acc[i][j]=0.f;

  for (int k0=0;k0<K;k0+=16){
    float4 av, bv;
    if (k0+16 <= K){
      av = *(const float4*)(Ap+k0);
      bv = *(const float4*)(Bp+k0);
    } else {
      float a0[4], b0[4];
      #pragma unroll
      for (int j=0;j<4;j++){
        int kk = k0+lk+j;
        a0[j] = (kk<K)? Ap[k0+j] : 0.f;
        b0[j] = (kk<K)? Bp[k0+j] : 0.f;
      }
      av = make_float4(a0[0],a0[1],a0[2],a0[3]);
      bv = make_float4(b0[0],b0[1],b0[2],b0[3]);
    }
    __syncthreads();
    As[lk+0][lm]=av.x; As[lk+1][lm]=av.y; As[lk+2][lm]=av.z; As[lk+3][lm]=av.w;
    Bs[lk+0][lm]=bv.x; Bs[lk+1][lm]=bv.y; Bs[lk+2][lm]=bv.z; Bs[lk+3][lm]=bv.w;
    __syncthreads();
    #pragma unroll
    for (int kk=0;kk<16;kk++){
      const float4 a = *(const float4*)(&As[kk][ty<<2]);
      const float4 b = *(const float4*)(&Bs[kk][tx<<2]);
      acc[0][0]+=a.x*b.x; acc[0][1]+=a.x*b.y; acc[0][2]+=a.x*b.z; acc[0][3]+=a.x*b.w;
      acc[1][0]+=a.y*b.x; acc[1][1]+=a.y*b.y; acc[1][2]+=a.y*b.z; acc[1][3]+=a.y*b.w;
      acc[2][0]+=a.z*b.x; acc[2][1]+=a.z*b.y; acc[2][2]+=a.z*b.z; acc[2][3]+=a.z*b.w;
      acc[3][0]+=a.w*b.x; acc[3][1]+=a.w*b.y; acc[3][2]+=a.w*b.z; acc[3][3]+=a.w*b.w;
    }
  }
  const int cm = bm+(ty<<2), cn = bn+(tx<<2);
  #pragma unroll
  for (int i=0;i<4;i++){
    #pragma unroll
    for (int j=0;j<4;j++){
      float v = acc[i][j] + (bias ? bias[cn+j] : 0.f);
      int col = cn+j;
      int pc = gperm ? (((col&255)<<2) | (col>>8)) : col;
      if (Cb) Cb[(size_t)(cm+i)*ldc + pc] = __float2bfloat16(v);
      else    Cf[(size_t)(cm+i)*ldc + pc] = v;
    }
  }
}

// -------------------- persistent bidirectional LSTM scan --------------------
// R11 structure — best verified configuration (scan 3116us, absmax 0.00195).
// 2 blocks, 512 threads (8 waves, 2/SIMD). Thread (j=tid>>1, q2=tid&1) owns
// all 4 gate rows of unit j over k-half [128*q2,128*q2+128): 128 i8-packed
// weight ints (allocator keeps ~88 arch-resident, rest AGPR-parked; the
// restore cost is the measured register-file floor after 7 redesigns).
// DPP quad_perm pair exchanges (pure VALU), double-buffered i8 h in LDS,
// ONE barrier/step.
__global__ __attribute__((amdgpu_flat_work_group_size(512,512), amdgpu_waves_per_eu(2,2)))
void lstm_scan(
    const __hip_bfloat16* __restrict__ preF,   // [LEN][1024] gate-permuted [s][4j+g]
    const __hip_bfloat16* __restrict__ preB,
    const signed char* __restrict__ Wq,        // [2][1024][256] rows g*256+j
    const float* __restrict__ wsc,             // [2][1024]
    float* __restrict__ hs, float* __restrict__ ht)
{
  const int dir = blockIdx.x;
  const int tid = threadIdx.x;   // 0..511
  const int j  = tid >> 1;       // unit 0..255
  const int q2 = tid & 1;        // k-half 0..1
  __shared__ int hq[2][64];      // double-buffered 256 x i8 h

  const signed char* wp = Wq + (size_t)dir*G4*HALF;
  const int4* p0 = (const int4*)(wp + (size_t)(0*HALF + j)*HALF + q2*128);
  const int4* p1 = (const int4*)(wp + (size_t)(1*HALF + j)*HALF + q2*128);
  const int4* p2 = (const int4*)(wp + (size_t)(2*HALF + j)*HALF + q2*128);
  const int4* p3 = (const int4*)(wp + (size_t)(3*HALF + j)*HALF + q2*128);
  int4 wA0=p0[0],wA1=p0[1],wA2=p0[2],wA3=p0[3],wA4=p0[4],wA5=p0[5],wA6=p0[6],wA7=p0[7];
  int4 wB0=p1[0],wB1=p1[1],wB2=p1[2],wB3=p1[3],wB4=p1[4],wB5=p1[5],wB6=p1[6],wB7=p1[7];
  int4 wC0=p2[0],wC1=p2[1],wC2=p2[2],wC3=p2[3],wC4=p2[4],wC5=p2[5],wC6=p2[6],wC7=p2[7];
  int4 wD0=p3[0],wD1=p3[1],wD2=p3[2],wD3=p3[3],wD4=p3[4],wD5=p3[5],wD6=p3[6],wD7=p3[7];
#define PIN(v) asm volatile("" : "+v"(v.x),"+v"(v.y),"+v"(v.z),"+v"(v.w))
  PIN(wA0);PIN(wA1);PIN(wA2);PIN(wA3);PIN(wA4);PIN(wA5);PIN(wA6);PIN(wA7);
  PIN(wB0);PIN(wB1);PIN(wB2);PIN(wB3);PIN(wB4);PIN(wB5);PIN(wB6);PIN(wB7);
  PIN(wC0);PIN(wC1);PIN(wC2);PIN(wC3);PIN(wC4);PIN(wC5);PIN(wC6);PIN(wC7);
  PIN(wD0);PIN(wD1);PIN(wD2);PIN(wD3);PIN(wD4);PIN(wD5);PIN(wD6);PIN(wD7);
#undef PIN

  // lane q2 computes gates {2*q2, 2*q2+1}: lane0 -> (i,f), lane1 -> (g~,o)
  const float scA = wsc[dir*G4 + (2*q2+0)*HALF + j];
  const float scB = wsc[dir*G4 + (2*q2+1)*HALF + j];
  const float eK0 = q2 ? -2.f : -1.f;    // slot0: sigmoid (lane0) / tanh (lane1)
  const float aM0 = q2 ?  2.f :  1.f;
  const float aB0 = q2 ? -1.f :  0.f;

  const int t0 = dir ? (LEN-1) : 0;
  const int pstep = dir ? -(G4/2) : (G4/2);     // row stride in uints
  const unsigned* pp = (const unsigned*)(dir ? preB : preF) + (size_t)t0*(G4/2) + tid;
  float* hsp = hs + (size_t)t0*HID + dir*HALF + j;
  const int hstep = dir ? -HID : HID;

  if (tid < 64) hq[0][tid] = 0;
  float c = 0.f;
  unsigned pv = *pp;
  __syncthreads();

  for (int s=0;s<LEN;s++){
    unsigned pnext = 0;
    if (s < LEN-1){ pp += pstep; pnext = *pp; }
    const int4* hb = (const int4*)(&hq[s&1][0]) + q2*8;
    int a0=0,a1=0,a2=0,a3=0;
#define CHUNK(i, A,B,C,D) { int4 hv = hb[i]; \
    a0=dot4(A.x,hv.x,a0); a0=dot4(A.y,hv.y,a0); a0=dot4(A.z,hv.z,a0); a0=dot4(A.w,hv.w,a0); \
    a1=dot4(B.x,hv.x,a1); a1=dot4(B.y,hv.y,a1); a1=dot4(B.z,hv.z,a1); a1=dot4(B.w,hv.w,a1); \
    a2=dot4(C.x,hv.x,a2); a2=dot4(C.y,hv.y,a2); a2=dot4(C.z,hv.z,a2); a2=dot4(C.w,hv.w,a2); \
    a3=dot4(D.x,hv.x,a3); a3=dot4(D.y,hv.y,a3); a3=dot4(D.z,hv.z,a3); a3=dot4(D.w,hv.w,a3); }
    CHUNK(0, wA0,wB0,wC0,wD0)
    CHUNK(1, wA1,wB1,wC1,wD1)
    CHUNK(2, wA2,wB2,wC2,wD2)
    CHUNK(3, wA3,wB3,wC3,wD3)
    CHUNK(4, wA4,wB4,wC4,wD4)
    CHUNK(5, wA5,wB5,wC5,wD5)
    CHUNK(6, wA6,wB6,wC6,wD6)
    CHUNK(7, wA7,wB7,wC7,wD7)
#undef CHUNK
    // ---- DPP pair transpose-reduce over the lane pair ----
    // lane0 wants full a0,a1 (i,f); lane1 wants full a2,a3 (g~,o)
    int r0 = dpp1i(q2 ? a0 : a2);
    int s0 = (q2 ? a2 : a0) + r0;          // lane0: i pre-sum; lane1: g~ pre-sum
    int r1 = dpp1i(q2 ? a1 : a3);
    int s1 = (q2 ? a3 : a1) + r1;          // lane0: f pre-sum; lane1: o pre-sum
    // ---- 2 nonlinearities per thread ----
    float g0v = bf2f((unsigned short)(pv & 0xffffu))  + (float)s0*scA;
    float g1v = bf2f((unsigned short)(pv >> 16))      + (float)s1*scB;
    float y0  = RCPF(1.f + __expf(eK0 * g0v));
    float act0 = fmaf(aM0, y0, aB0);       // lane0: i ; lane1: g~
    float act1 = sigm_(g1v);               // lane0: f ; lane1: o
    // ---- bring (g~, o) to lane0 via DPP ----
    float gg = dpp1f(act0);                // lane0: g~
    float oo = dpp1f(act1);                // lane0: o
    if (q2 == 0){
      c = fmaf(act1, c, act0 * gg);
      float h = oo * tanh_(c);
      *hsp = h;
      ((signed char*)&hq[(s+1)&1][0])[j] = (signed char)__float2int_rn(h * 127.f);
      if (s == LEN-1) ht[dir*HALF + j] = h;
    }
    hsp += hstep;
    pv = pnext;
    __syncthreads();
  }
}

// ---------------- xw = ht @ W_x_a^T + b_x_a [512] ---------------------------
__global__ __launch_bounds__(512) void xw_kernel(const float* __restrict__ ht,
    const float* __restrict__ Wx, const float* __restrict__ bx, float* __restrict__ xw)
{
  __shared__ float h[HID];
  const int tid = threadIdx.x;
  h[tid] = ht[tid];
  __syncthreads();
  const float* wr = Wx + (size_t)tid*HID;
  float d = 0.f;
  for (int k=0;k<HID;k++) d += h[k]*wr[k];
  xw[tid] = d + bx[tid];
}

// ------- scores[o,l] = w_a . tanh(Wh_out[l] + Wv_ae[o]) + b_w_a -------------
__global__ __launch_bounds__(256) void scores_kernel(
    const float* __restrict__ WhOut, const float* __restrict__ WvAE,
    const float* __restrict__ wa, const float* __restrict__ bwa,
    float* __restrict__ scores)
{
  __shared__ float red[4];
  const int l = blockIdx.x, tid = threadIdx.x;
  const int lane = tid & 63, wv = tid >> 6;
  const float wl0 = WhOut[(size_t)l*HID + tid];
  const float wl1 = WhOut[(size_t)l*HID + 256 + tid];
  const float wa0 = wa[tid], wa1 = wa[256+tid];
  const float bb = bwa[0];
  for (int o=0;o<OUT_N;o++){
    float v = wa0*tanh_(wl0 + WvAE[o*HID+tid]) + wa1*tanh_(wl1 + WvAE[o*HID+256+tid]);
    #pragma unroll
    for (int m=32;m;m>>=1) v += __shfl_xor(v, m, 64);
    if (lane==0) red[wv] = v;
    __syncthreads();
    if (tid==0) scores[(size_t)o*LEN + l] = red[0]+red[1]+red[2]+red[3] + bb;
    __syncthreads();
  }
}

// ------- softmax over l (per o) + r[o] = weights @ output2 ------------------
__global__ __launch_bounds__(512) void softmax_wsum(
    const float* __restrict__ scores, const float* __restrict__ hs, float* __restrict__ ratt)
{
  __shared__ float sm[LEN];
  __shared__ float red[8];
  __shared__ float bc[2];
  const int o = blockIdx.x, tid = threadIdx.x;
  const int lane = tid & 63, wv = tid >> 6;
  for (int l=tid;l<LEN;l+=512) sm[l] = scores[(size_t)o*LEN + l];
  __syncthreads();
  float mx = -1e30f;
  for (int l=tid;l<LEN;l+=512) mx = fmaxf(mx, sm[l]);
  #pragma unroll
  for (int m=32;m;m>>=1) mx = fmaxf(mx, __shfl_xor(mx, m, 64));
  if (lane==0) red[wv] = mx;
  __syncthreads();
  if (tid==0){ float m0=red[0]; for (int i=1;i<8;i++) m0=fmaxf(m0,red[i]); bc[0]=m0; }
  __syncthreads();
  const float m0 = bc[0];
  float s = 0.f;
  for (int l=tid;l<LEN;l+=512){ float e = __expf(sm[l]-m0); sm[l]=e; s+=e; }
  #pragma unroll
  for (int m=32;m;m>>=1) s += __shfl_xor(s, m, 64);
  if (lane==0) red[wv] = s;
  __syncthreads();
  if (tid==0){ float z=0.f; for (int i=0;i<8;i++) z+=red[i]; bc[1] = 1.f/z; }
  __syncthreads();
  const float rz = bc[1];
  float acc = 0.f;
  const float* hp = hs + tid;
  for (int l=0;l<LEN;l++) acc += sm[l]*hp[(size_t)l*HID];
  ratt[(size_t)o*HID + tid] = acc*rz;
}

// ------- out[o] = sigmoid( dec_W[o] . tanh(r W_p^T + b_p + xw) + dec_b ) ----
__global__ __launch_bounds__(256) void final_kernel(
    const float* __restrict__ ratt, const float* __restrict__ Wp, const float* __restrict__ bp,
    const float* __restrict__ xw, const float* __restrict__ decW, const float* __restrict__ decb,
    float* __restrict__ outp)
{
  __shared__ float rv[HID];
  __shared__ float rr[HID];
  __shared__ float red[4];
  const int o = blockIdx.x, tid = threadIdx.x;
  const int lane = tid & 63, wv = tid >> 6;
  rv[tid]     = ratt[(size_t)o*HID + tid];
  rv[256+tid] = ratt[(size_t)o*HID + 256 + tid];
  __syncthreads();
  #pragma unroll
  for (int jj=0;jj<2;jj++){
    int j = tid + jj*256;
    const float* wr = Wp + (size_t)j*HID;
    float d = 0.f;
    for (int k=0;k<HID;k++) d += rv[k]*wr[k];
    rr[j] = tanh_(d + bp[j] + xw[j]);
  }
  __syncthreads();
  float v = rr[tid]*decW[(size_t)o*HID+tid] + rr[256+tid]*decW[(size_t)o*HID+256+tid];
  #pragma unroll
  for (int m=32;m;m>>=1) v += __shfl_xor(v, m, 64);
  if (lane==0) red[wv] = v;
  __syncthreads();
  if (tid==0) outp[o] = sigm_(red[0]+red[1]+red[2]+red[3] + decb[o]);
}

// ---------------------------------------------------------------------------
extern "C" void kernel_launch(void* const* d_in, const int* in_sizes, int n_in,
                              void* d_out, int out_size, void* d_ws, size_t ws_size,
                              hipStream_t stream)
{
  (void)in_sizes; (void)n_in; (void)out_size; (void)ws_size;
  const int*   sent  = (const int*)  d_in[0];
  const float* embed = (const float*)d_in[1];
  const float* WihF  = (const float*)d_in[2];
  const float* WhhF  = (const float*)d_in[3];
  const float* bihF  = (const float*)d_in[4];
  const float* bhhF  = (const float*)d_in[5];
  const float* WihB  = (const float*)d_in[6];
  const float* WhhB  = (const float*)d_in[7];
  const float* bihB  = (const float*)d_in[8];
  const float* bhhB  = (const float*)d_in[9];
  const float* AE    = (const float*)d_in[10];
  const float* W_h   = (const float*)d_in[11];
  const float* b_h   = (const float*)d_in[12];
  const float* W_v   = (const float*)d_in[13];
  const float* b_v   = (const float*)d_in[14];
  const float* w_a   = (const float*)d_in[15];
  const float* b_w   = (const float*)d_in[16];
  const float* W_p   = (const float*)d_in[17];
  const float* b_p   = (const float*)d_in[18];
  const float* W_x   = (const float*)d_in[19];
  const float* b_x   = (const float*)d_in[20];
  const float* decW  = (const float*)d_in[21];
  const float* decb  = (const float*)d_in[22];
  float* outp = (float*)d_out;

  char* ws = (char*)d_ws;
  size_t off = 0;
  auto alloc = [&](size_t n){ size_t p = off; off += (n + 255) & ~(size_t)255; return p; };
  __hip_bfloat16* preF  = (__hip_bfloat16*)(ws + alloc((size_t)LEN*G4*2));
  __hip_bfloat16* preB  = (__hip_bfloat16*)(ws + alloc((size_t)LEN*G4*2));
  float*          hsbuf = (float*)        (ws + alloc((size_t)LEN*HID*4));
  float*          WhOut = (float*)        (ws + alloc((size_t)LEN*HID*4));
  signed char*    Wq    = (signed char*)  (ws + alloc((size_t)2*G4*HALF));
  float*          wsc   = (float*)        (ws + alloc((size_t)2*G4*4));
  float*          bsum  = (float*)        (ws + alloc((size_t)2*G4*4));
  float*          htv   = (float*)        (ws + alloc((size_t)HID*4));
  float*          WvAE  = (float*)        (ws + alloc((size_t)OUT_N*HID*4));
  float*          xw    = (float*)        (ws + alloc((size_t)HID*4));
  float*          scor  = (float*)        (ws + alloc((size_t)OUT_N*LEN*4));
  float*          ratt  = (float*)        (ws + alloc((size_t)OUT_N*HID*4));

  // prep
  prep_quant<<<8, 256, 0, stream>>>(WhhF, WhhB, bihF, bhhF, bihB, bhhB, Wq, wsc, bsum);
  wv_kernel<<<OUT_N, 256, 0, stream>>>(AE, W_v, b_v, WvAE);

  // pre = gather(embed, sent) @ Wih^T + (bih+bhh), bf16, gate-permuted cols
  gemm_tn<<<dim3(LEN/64, G4/64), 256, 0, stream>>>(
      embed, EMB, sent, WihF, EMB, bsum,        nullptr, preF, G4, LEN, G4, EMB, 1);
  gemm_tn<<<dim3(LEN/64, G4/64), 256, 0, stream>>>(
      embed, EMB, sent, WihB, EMB, bsum + G4,   nullptr, preB, G4, LEN, G4, EMB, 1);

  // sequential bidirectional scan (2 persistent blocks, 512 threads each)
  lstm_scan<<<2, 512, 0, stream>>>(preF, preB, Wq, wsc, hsbuf, htv);

  // Wh_out = output2 @ W_h_a^T + b_h_a
  gemm_tn<<<dim3(LEN/64, HID/64), 256, 0, stream>>>(
      hsbuf, HID, nullptr, W_h, HID, b_h, WhOut, nullptr, HID, LEN, HID, HID, 0);

  xw_kernel<<<1, 512, 0, stream>>>(htv, W_x, b_x, xw);
  scores_kernel<<<LEN, 256, 0, stream>>>(WhOut, WvAE, w_a, b_w, scor);
  softmax_wsum<<<OUT_N, 512, 0, stream>>>(scor, hsbuf, ratt);
  final_kernel<<<OUT_N, 256, 0, stream>>>(ratt, W_p, b_p, xw, decW, decb, outp);
}